// Round 4
// baseline (624.866 us; speedup 1.0000x reference)
//
#include <hip/hip_runtime.h>
#include <hip/hip_bf16.h>
#include <hip/hip_fp16.h>

#define B_ 2
#define T_ 2048
#define DM 1024
#define H_ 16
#define HD_ 64

typedef __attribute__((ext_vector_type(8))) short bf16x8v;
typedef __attribute__((ext_vector_type(4))) short short4v;
typedef __attribute__((ext_vector_type(4))) float f32x4;

__device__ __forceinline__ short f2bf(float f){
  unsigned u = __builtin_bit_cast(unsigned, f);
  u += 0x7fffu + ((u >> 16) & 1u);
  return (short)(u >> 16);
}
__device__ __forceinline__ float bf2f(short s){
  unsigned u = ((unsigned)(unsigned short)s) << 16;
  return __builtin_bit_cast(float, u);
}

#define GLOAD_LDS16(g, l) \
  __builtin_amdgcn_global_load_lds((const __attribute__((address_space(1))) unsigned int*)(g), \
                                   (__attribute__((address_space(3))) unsigned int*)(l), 16, 0, 0)

#define MFMA16(a, b, c) __builtin_amdgcn_mfma_f32_16x16x32_bf16((a), (b), (c), 0, 0, 0)

// ---------------------------------------------------------------------------
// fp32 -> bf16 conversion for 3 activations (4M elems) + 4 weights (1M elems)
// ---------------------------------------------------------------------------
__global__ __launch_bounds__(256) void conv_kernel(
    const float* __restrict__ s0, const float* __restrict__ s1, const float* __restrict__ s2,
    const float* __restrict__ s3, const float* __restrict__ s4, const float* __restrict__ s5,
    const float* __restrict__ s6,
    short* __restrict__ d0, short* __restrict__ d1, short* __restrict__ d2,
    short* __restrict__ d3, short* __restrict__ d4, short* __restrict__ d5,
    short* __restrict__ d6)
{
  int y = blockIdx.y;
  const float* s; short* d; int n;
  switch (y) {
    case 0: s = s0; d = d0; n = B_*T_*DM; break;
    case 1: s = s1; d = d1; n = B_*T_*DM; break;
    case 2: s = s2; d = d2; n = B_*T_*DM; break;
    case 3: s = s3; d = d3; n = DM*DM;   break;
    case 4: s = s4; d = d4; n = DM*DM;   break;
    case 5: s = s5; d = d5; n = DM*DM;   break;
    default: s = s6; d = d6; n = DM*DM;  break;
  }
  int i = (blockIdx.x * 256 + threadIdx.x) * 4;
  if (i >= n) return;
  float4 f = *(const float4*)(s + i);
  short4v o;
  o.x = f2bf(f.x); o.y = f2bf(f.y); o.z = f2bf(f.z); o.w = f2bf(f.w);
  *(short4v*)(d + i) = o;
}

// ---------------------------------------------------------------------------
// Projection GEMM: C = X(4096x1024) * W^T(1024x1024), bf16 MFMA, 128x128 tile.
// z=0: Q (scaled 1/8) -> [b,h,t,hd]; z=1: K -> [b,h,t,hd]; z=2: V -> [b,h,hd,t]
// ---------------------------------------------------------------------------
__global__ __launch_bounds__(256) void proj_gemm(
    const short* __restrict__ xq, const short* __restrict__ xk, const short* __restrict__ xv,
    const short* __restrict__ wq, const short* __restrict__ wk, const short* __restrict__ wv,
    short* __restrict__ qo, short* __restrict__ ko, short* __restrict__ vto)
{
  __shared__ short As[128 * 32];
  __shared__ short Bs[128 * 32];
  const int z = blockIdx.z;
  const short* A  = (z == 0) ? xq : (z == 1) ? xk : xv;
  const short* Bw = (z == 0) ? wq : (z == 1) ? wk : wv;
  const int m0 = blockIdx.x * 128;
  const int n0 = blockIdx.y * 128;
  const int tid = threadIdx.x;
  const int w = tid >> 6, l = tid & 63;
  const int wr = w >> 1, wc = w & 1;
  const int fr = l & 15, kq8 = (l >> 4) * 8;
  const int srow = tid >> 2, scol = (tid & 3) * 8;

  f32x4 acc[4][4] = {};

  for (int k0 = 0; k0 < DM; k0 += 32) {
    __syncthreads();
    GLOAD_LDS16(A  + (size_t)(m0 + srow) * DM + k0 + scol,      (char*)As + tid * 16);
    GLOAD_LDS16(A  + (size_t)(m0 + 64 + srow) * DM + k0 + scol, (char*)As + 4096 + tid * 16);
    GLOAD_LDS16(Bw + (size_t)(n0 + srow) * DM + k0 + scol,      (char*)Bs + tid * 16);
    GLOAD_LDS16(Bw + (size_t)(n0 + 64 + srow) * DM + k0 + scol, (char*)Bs + 4096 + tid * 16);
    __syncthreads();
    bf16x8v a[4], b[4];
#pragma unroll
    for (int i = 0; i < 4; i++) a[i] = *(const bf16x8v*)&As[(wr * 64 + i * 16 + fr) * 32 + kq8];
#pragma unroll
    for (int j = 0; j < 4; j++) b[j] = *(const bf16x8v*)&Bs[(wc * 64 + j * 16 + fr) * 32 + kq8];
#pragma unroll
    for (int i = 0; i < 4; i++)
#pragma unroll
      for (int j = 0; j < 4; j++)
        acc[i][j] = MFMA16(a[i], b[j], acc[i][j]);
  }

  const float scale = (z == 0) ? 0.125f : 1.0f;
  short* dst01 = (z == 0) ? qo : ko;
#pragma unroll
  for (int i = 0; i < 4; i++) {
#pragma unroll
    for (int j = 0; j < 4; j++) {
#pragma unroll
      for (int r = 0; r < 4; r++) {
        int row = m0 + wr * 64 + i * 16 + (l >> 4) * 4 + r;
        int col = n0 + wc * 64 + j * 16 + fr;
        int bb = row >> 11, tt = row & (T_ - 1);
        int hh = col >> 6,  hd = col & (HD_ - 1);
        short v = f2bf(acc[i][j][r] * scale);
        if (z == 2)
          vto[(((size_t)bb * H_ + hh) * HD_ + hd) * T_ + tt] = v;
        else
          dst01[(((size_t)bb * H_ + hh) * T_ + tt) * HD_ + hd] = v;
      }
    }
  }
}

// ---------------------------------------------------------------------------
// Column sums of V (for fully-masked rows): vs[bh*64+hd] = sum_t V[bh][t][hd]
// ---------------------------------------------------------------------------
__global__ __launch_bounds__(256) void vsum_kernel(const short* __restrict__ vt,
                                                   float* __restrict__ vs)
{
  __shared__ float red[256];
  int bh = blockIdx.x;
  int tid = threadIdx.x;
  int hd = tid & 63, part = tid >> 6;
  const short* src = vt + ((size_t)bh * HD_ + hd) * T_ + part * 512;
  float s = 0.f;
  for (int i = 0; i < 512; i += 4) {
    short4v v = *(const short4v*)(src + i);
    s += bf2f(v.x) + bf2f(v.y) + bf2f(v.z) + bf2f(v.w);
  }
  red[tid] = s;
  __syncthreads();
  if (part == 0)
    vs[(size_t)bh * HD_ + hd] = red[hd] + red[64 + hd] + red[128 + hd] + red[192 + hd];
}

// ---------------------------------------------------------------------------
// Attention, barrier-free two-pass flash style.
// One wave owns 16 q-rows of one (b,h). Pass 1: online max/sum in registers.
// Pass 2: recompute scores, normalize, transpose via per-wave LDS for
// coalesced NT attn stores, repack bf16 and accumulate P.V via MFMA.
// Grid (T/16/4, B, H), 256 threads (4 waves, q-tiles interleaved w*32+bx).
// ---------------------------------------------------------------------------
__global__ __launch_bounds__(256, 4) void attn_kernel(
    const short* __restrict__ qw, const short* __restrict__ kw, const short* __restrict__ vt,
    const float* __restrict__ bias, const int* __restrict__ mask,
    const int* __restrict__ causal_p, const float* __restrict__ vsum,
    float* __restrict__ attn_out, short* __restrict__ outh)
{
  __shared__ float s_t[4][16][68];   // per-wave fp32 transpose buffer
  __shared__ short p_l[4][16][72];   // per-wave bf16 p tile (A-frag source)
  __shared__ float fm_l[4][16];      // per-wave row max (fullmask detect)

  const int tid = threadIdx.x;
  const int w = tid >> 6, l = tid & 63;
  const int fr = l & 15, q4 = l >> 4, kq8 = q4 * 8;
  const int b = blockIdx.y, h = blockIdx.z;
  const int qt = w * 32 + blockIdx.x;       // q-tile index 0..127
  const int q0w = qt * 16;
  const int causal = *causal_p;
  const int L = causal ? (q0w + 16) : T_;
  const int KEND = (L + 63) & ~63;
  const size_t bh = (size_t)b * H_ + h;
  const short* Kb = kw + bh * T_ * HD_;
  const short* Vb = vt + bh * HD_ * T_;
  const int* mrow = mask + b * T_;
  const float* biasb = bias + ((size_t)h * T_ + q0w) * T_;
  float* arowb = attn_out + (bh * T_ + q0w) * T_;
  const float invT = 1.0f / (float)T_;

  // Q fragments: A[m=fr (q-row), k]
  bf16x8v qa0, qa1;
  {
    const short* qp = qw + (bh * T_ + q0w + fr) * HD_;
    qa0 = *(const bf16x8v*)(qp + kq8);
    qa1 = *(const bf16x8v*)(qp + 32 + kq8);
  }

  float m4[4], l4[4];
#pragma unroll
  for (int r = 0; r < 4; r++) { m4[r] = -3e38f; l4[r] = 0.f; }

  // ---------------- pass 1: online row max + sum ----------------
  for (int k0 = 0; k0 < KEND; k0 += 64) {
    f32x4 s[4] = {};
#pragma unroll
    for (int t = 0; t < 4; t++) {
      const short* kp = Kb + (size_t)(k0 + t * 16 + fr) * HD_ + kq8;
      bf16x8v kf0 = *(const bf16x8v*)kp;
      bf16x8v kf1 = *(const bf16x8v*)(kp + 32);
      s[t] = MFMA16(qa0, kf0, s[t]);
      s[t] = MFMA16(qa1, kf1, s[t]);
      int kcol = k0 + t * 16 + fr;
      int mk = mrow[kcol];
      const float* bp = biasb + (size_t)(q4 * 4) * T_ + kcol;
#pragma unroll
      for (int r = 0; r < 4; r++) {
        float bi = bp[(size_t)r * T_];
        bool ok = (mk != 0) && (!causal || kcol <= q0w + q4 * 4 + r);
        s[t][r] = ok ? (s[t][r] + bi) : -1e9f;
      }
    }
#pragma unroll
    for (int r = 0; r < 4; r++) {
      float tmax = fmaxf(fmaxf(s[0][r], s[1][r]), fmaxf(s[2][r], s[3][r]));
      float nm = fmaxf(m4[r], tmax);
      float sc = __expf(m4[r] - nm);
      float sum = __expf(s[0][r] - nm) + __expf(s[1][r] - nm) +
                  __expf(s[2][r] - nm) + __expf(s[3][r] - nm);
      l4[r] = l4[r] * sc + sum;
      m4[r] = nm;
    }
  }
  // reduce across the 16 k-lanes (fr)
#pragma unroll
  for (int r = 0; r < 4; r++) {
#pragma unroll
    for (int off = 1; off < 16; off <<= 1) {
      float om = __shfl_xor(m4[r], off);
      float ol = __shfl_xor(l4[r], off);
      float nm = fmaxf(m4[r], om);
      l4[r] = l4[r] * __expf(m4[r] - nm) + ol * __expf(om - nm);
      m4[r] = nm;
    }
  }
  float inv4[4];
#pragma unroll
  for (int r = 0; r < 4; r++) inv4[r] = 1.0f / l4[r];
  if (fr == 0) {
#pragma unroll
    for (int r = 0; r < 4; r++) fm_l[w][q4 * 4 + r] = m4[r];
  }

  // ---------------- pass 2: p, coalesced NT store, P.V ----------------
  f32x4 oacc[4] = {};
  for (int k0 = 0; k0 < KEND; k0 += 64) {
    f32x4 s[4] = {};
#pragma unroll
    for (int t = 0; t < 4; t++) {
      const short* kp = Kb + (size_t)(k0 + t * 16 + fr) * HD_ + kq8;
      bf16x8v kf0 = *(const bf16x8v*)kp;
      bf16x8v kf1 = *(const bf16x8v*)(kp + 32);
      s[t] = MFMA16(qa0, kf0, s[t]);
      s[t] = MFMA16(qa1, kf1, s[t]);
      int kcol = k0 + t * 16 + fr;
      int mk = mrow[kcol];
      const float* bp = biasb + (size_t)(q4 * 4) * T_ + kcol;
#pragma unroll
      for (int r = 0; r < 4; r++) {
        float bi = bp[(size_t)r * T_];
        bool ok = (mk != 0) && (!causal || kcol <= q0w + q4 * 4 + r);
        s[t][r] = ok ? (s[t][r] + bi) : -1e9f;
      }
    }
    // p in C-layout -> fp32 LDS
#pragma unroll
    for (int t = 0; t < 4; t++)
#pragma unroll
      for (int r = 0; r < 4; r++)
        s_t[w][q4 * 4 + r][t * 16 + fr] = __expf(s[t][r] - m4[r]) * inv4[r];
    // transpose read -> NT global store + bf16 LDS for PV
#pragma unroll
    for (int j = 0; j < 4; j++) {
      int row = 4 * j + q4;
      f32x4 pv = *(const f32x4*)&s_t[w][row][fr * 4];
      bool fmj = fm_l[w][row] <= -0.5e9f;
      f32x4 ov;
      ov[0] = fmj ? invT : pv[0];
      ov[1] = fmj ? invT : pv[1];
      ov[2] = fmj ? invT : pv[2];
      ov[3] = fmj ? invT : pv[3];
      __builtin_nontemporal_store(ov, (f32x4*)(arowb + (size_t)row * T_ + k0 + fr * 4));
      short4v pb;
      pb.x = f2bf(pv[0]); pb.y = f2bf(pv[1]); pb.z = f2bf(pv[2]); pb.w = f2bf(pv[3]);
      *(short4v*)&p_l[w][row][fr * 4] = pb;
    }
    // P.V MFMA: A = p rows (m=fr), B = V^T rows (n=fr)
#pragma unroll
    for (int ks = 0; ks < 2; ks++) {
      bf16x8v pa = *(const bf16x8v*)&p_l[w][fr][ks * 32 + kq8];
#pragma unroll
      for (int n0 = 0; n0 < 4; n0++) {
        bf16x8v vv = *(const bf16x8v*)&Vb[(size_t)(n0 * 16 + fr) * T_ + k0 + ks * 32 + kq8];
        oacc[n0] = MFMA16(pa, vv, oacc[n0]);
      }
    }
  }

  // out_h write (C-layout: row=q4*4+r, col=n0*16+fr)
#pragma unroll
  for (int n0 = 0; n0 < 4; n0++) {
#pragma unroll
    for (int r = 0; r < 4; r++) {
      int row = q4 * 4 + r, col = n0 * 16 + fr;
      float val = oacc[n0][r];
      if (m4[r] <= -0.5e9f) val = vsum[bh * HD_ + col] * invT;
      outh[(bh * T_ + q0w + row) * HD_ + col] = f2bf(val);
    }
  }

  // tail fill [KEND, T)
  if (KEND < T_) {
#pragma unroll
    for (int j = 0; j < 4; j++) {
      int row = 4 * j + q4;
      float fill = (fm_l[w][row] <= -0.5e9f) ? invT : 0.f;
      f32x4 fv = {fill, fill, fill, fill};
      float* rp = arowb + (size_t)row * T_;
      for (int c = KEND + fr * 4; c < T_; c += 64)
        __builtin_nontemporal_store(fv, (f32x4*)(rp + c));
    }
  }
}

// ---------------------------------------------------------------------------
// Output GEMM: out = out_h(4096x1024 logical) * Wo^T, fp32 output
// ---------------------------------------------------------------------------
__global__ __launch_bounds__(256) void out_gemm(
    const short* __restrict__ Ah, const short* __restrict__ Bw, float* __restrict__ Co)
{
  __shared__ short As[128 * 32];
  __shared__ short Bs[128 * 32];
  const int m0 = blockIdx.x * 128;
  const int n0 = blockIdx.y * 128;
  const int tid = threadIdx.x;
  const int w = tid >> 6, l = tid & 63;
  const int wr = w >> 1, wc = w & 1;
  const int fr = l & 15, kq8 = (l >> 4) * 8;
  const int srow = tid >> 2, scol = (tid & 3) * 8;

  f32x4 acc[4][4] = {};

  for (int k0 = 0; k0 < DM; k0 += 32) {
    __syncthreads();
    int kk = k0 + scol;
    int hh = kk >> 6, hd = kk & 63;
    {
      int m1 = m0 + srow;
      const short* src1 = Ah + (((size_t)(m1 >> 11) * H_ + hh) * T_ + (m1 & (T_ - 1))) * HD_ + hd;
      GLOAD_LDS16(src1, (char*)As + tid * 16);
      int m2 = m0 + 64 + srow;
      const short* src2 = Ah + (((size_t)(m2 >> 11) * H_ + hh) * T_ + (m2 & (T_ - 1))) * HD_ + hd;
      GLOAD_LDS16(src2, (char*)As + 4096 + tid * 16);
    }
    GLOAD_LDS16(Bw + (size_t)(n0 + srow) * DM + kk,      (char*)Bs + tid * 16);
    GLOAD_LDS16(Bw + (size_t)(n0 + 64 + srow) * DM + kk, (char*)Bs + 4096 + tid * 16);
    __syncthreads();
    bf16x8v a[4], b[4];
#pragma unroll
    for (int i = 0; i < 4; i++) a[i] = *(const bf16x8v*)&As[(wr * 64 + i * 16 + fr) * 32 + kq8];
#pragma unroll
    for (int j = 0; j < 4; j++) b[j] = *(const bf16x8v*)&Bs[(wc * 64 + j * 16 + fr) * 32 + kq8];
#pragma unroll
    for (int i = 0; i < 4; i++)
#pragma unroll
      for (int j = 0; j < 4; j++)
        acc[i][j] = MFMA16(a[i], b[j], acc[i][j]);
  }

#pragma unroll
  for (int i = 0; i < 4; i++)
#pragma unroll
    for (int j = 0; j < 4; j++)
#pragma unroll
      for (int r = 0; r < 4; r++) {
        int row = m0 + wr * 64 + i * 16 + (l >> 4) * 4 + r;
        int col = n0 + wc * 64 + j * 16 + fr;
        Co[(size_t)row * DM + col] = acc[i][j][r];
      }
}

// ---------------------------------------------------------------------------
extern "C" void kernel_launch(void* const* d_in, const int* in_sizes, int n_in,
                              void* d_out, int out_size, void* d_ws, size_t ws_size,
                              hipStream_t stream)
{
  const float* x_q  = (const float*)d_in[0];
  const float* x_k  = (const float*)d_in[1];
  const float* x_v  = (const float*)d_in[2];
  const int*   mask = (const int*)d_in[3];
  const int*   causal = (const int*)d_in[4];
  const float* bias = (const float*)d_in[5];
  const float* Wq   = (const float*)d_in[6];
  const float* Wk   = (const float*)d_in[7];
  const float* Wv   = (const float*)d_in[8];
  const float* Wo   = (const float*)d_in[9];

  char* ws = (char*)d_ws;
  const size_t XB = (size_t)B_ * T_ * DM * 2;   // 8 MB
  const size_t WB = (size_t)DM * DM * 2;        // 2 MB
  short* xq_b = (short*)(ws + 0 * XB);
  short* xk_b = (short*)(ws + 1 * XB);
  short* xv_b = (short*)(ws + 2 * XB);
  short* wq_b = (short*)(ws + 3 * XB + 0 * WB);
  short* wk_b = (short*)(ws + 3 * XB + 1 * WB);
  short* wv_b = (short*)(ws + 3 * XB + 2 * WB);
  short* wo_b = (short*)(ws + 3 * XB + 3 * WB);
  short* q_ws  = (short*)(ws + 3 * XB + 4 * WB);
  short* k_ws  = (short*)(ws + 4 * XB + 4 * WB);
  short* vt_ws = (short*)(ws + 5 * XB + 4 * WB);
  short* oh_ws = (short*)(ws + 6 * XB + 4 * WB);
  float* vs_ws = (float*)(ws + 7 * XB + 4 * WB);

  float* out0 = (float*)d_out;
  float* attn = out0 + (size_t)B_ * T_ * DM;

  conv_kernel<<<dim3(4096, 7, 1), 256, 0, stream>>>(
      x_q, x_k, x_v, Wq, Wk, Wv, Wo,
      xq_b, xk_b, xv_b, wq_b, wk_b, wv_b, wo_b);

  proj_gemm<<<dim3(32, 8, 3), 256, 0, stream>>>(
      xq_b, xk_b, xv_b, wq_b, wk_b, wv_b, q_ws, k_ws, vt_ws);

  vsum_kernel<<<dim3(32, 1, 1), 256, 0, stream>>>(vt_ws, vs_ws);

  attn_kernel<<<dim3(T_ / 16 / 4, B_, H_), 256, 0, stream>>>(
      q_ws, k_ws, vt_ws, bias, mask, causal, vs_ws, attn, oh_ws);

  out_gemm<<<dim3(32, 8, 1), 256, 0, stream>>>(oh_ws, wo_b, out0);
}

// Round 5
// 485.475 us; speedup vs baseline: 1.2871x; 1.2871x over previous
//
#include <hip/hip_runtime.h>
#include <hip/hip_bf16.h>
#include <hip/hip_fp16.h>

#define B_ 2
#define T_ 2048
#define DM 1024
#define H_ 16
#define HD_ 64

typedef __attribute__((ext_vector_type(8))) short bf16x8v;
typedef __attribute__((ext_vector_type(4))) short short4v;
typedef __attribute__((ext_vector_type(4))) float f32x4;

__device__ __forceinline__ short f2bf(float f){
  unsigned u = __builtin_bit_cast(unsigned, f);
  u += 0x7fffu + ((u >> 16) & 1u);
  return (short)(u >> 16);
}
__device__ __forceinline__ float bf2f(short s){
  unsigned u = ((unsigned)(unsigned short)s) << 16;
  return __builtin_bit_cast(float, u);
}

#define GLOAD_LDS16(g, l) \
  __builtin_amdgcn_global_load_lds((const __attribute__((address_space(1))) unsigned int*)(g), \
                                   (__attribute__((address_space(3))) unsigned int*)(l), 16, 0, 0)

#define MFMA16(a, b, c) __builtin_amdgcn_mfma_f32_16x16x32_bf16((a), (b), (c), 0, 0, 0)

// ---------------------------------------------------------------------------
// fp32 -> bf16 conversion for 3 activations (4M elems) + 4 weights (1M elems)
// ---------------------------------------------------------------------------
__global__ __launch_bounds__(256) void conv_kernel(
    const float* __restrict__ s0, const float* __restrict__ s1, const float* __restrict__ s2,
    const float* __restrict__ s3, const float* __restrict__ s4, const float* __restrict__ s5,
    const float* __restrict__ s6,
    short* __restrict__ d0, short* __restrict__ d1, short* __restrict__ d2,
    short* __restrict__ d3, short* __restrict__ d4, short* __restrict__ d5,
    short* __restrict__ d6)
{
  int y = blockIdx.y;
  const float* s; short* d; int n;
  switch (y) {
    case 0: s = s0; d = d0; n = B_*T_*DM; break;
    case 1: s = s1; d = d1; n = B_*T_*DM; break;
    case 2: s = s2; d = d2; n = B_*T_*DM; break;
    case 3: s = s3; d = d3; n = DM*DM;   break;
    case 4: s = s4; d = d4; n = DM*DM;   break;
    case 5: s = s5; d = d5; n = DM*DM;   break;
    default: s = s6; d = d6; n = DM*DM;  break;
  }
  int i = (blockIdx.x * 256 + threadIdx.x) * 4;
  if (i >= n) return;
  float4 f = *(const float4*)(s + i);
  short4v o;
  o.x = f2bf(f.x); o.y = f2bf(f.y); o.z = f2bf(f.z); o.w = f2bf(f.w);
  *(short4v*)(d + i) = o;
}

// ---------------------------------------------------------------------------
// Projection GEMM: C = X(4096x1024) * W^T(1024x1024), bf16 MFMA, 128x128 tile.
// z=0: Q (scaled 1/8) -> [b,h,t,hd]; z=1: K -> [b,h,t,hd]; z=2: V -> [b,h,hd,t]
// ---------------------------------------------------------------------------
__global__ __launch_bounds__(256) void proj_gemm(
    const short* __restrict__ xq, const short* __restrict__ xk, const short* __restrict__ xv,
    const short* __restrict__ wq, const short* __restrict__ wk, const short* __restrict__ wv,
    short* __restrict__ qo, short* __restrict__ ko, short* __restrict__ vto)
{
  __shared__ short As[128 * 32];
  __shared__ short Bs[128 * 32];
  const int z = blockIdx.z;
  const short* A  = (z == 0) ? xq : (z == 1) ? xk : xv;
  const short* Bw = (z == 0) ? wq : (z == 1) ? wk : wv;
  const int m0 = blockIdx.x * 128;
  const int n0 = blockIdx.y * 128;
  const int tid = threadIdx.x;
  const int w = tid >> 6, l = tid & 63;
  const int wr = w >> 1, wc = w & 1;
  const int fr = l & 15, kq8 = (l >> 4) * 8;
  const int srow = tid >> 2, scol = (tid & 3) * 8;

  f32x4 acc[4][4] = {};

  for (int k0 = 0; k0 < DM; k0 += 32) {
    __syncthreads();
    GLOAD_LDS16(A  + (size_t)(m0 + srow) * DM + k0 + scol,      (char*)As + tid * 16);
    GLOAD_LDS16(A  + (size_t)(m0 + 64 + srow) * DM + k0 + scol, (char*)As + 4096 + tid * 16);
    GLOAD_LDS16(Bw + (size_t)(n0 + srow) * DM + k0 + scol,      (char*)Bs + tid * 16);
    GLOAD_LDS16(Bw + (size_t)(n0 + 64 + srow) * DM + k0 + scol, (char*)Bs + 4096 + tid * 16);
    __syncthreads();
    bf16x8v a[4], b[4];
#pragma unroll
    for (int i = 0; i < 4; i++) a[i] = *(const bf16x8v*)&As[(wr * 64 + i * 16 + fr) * 32 + kq8];
#pragma unroll
    for (int j = 0; j < 4; j++) b[j] = *(const bf16x8v*)&Bs[(wc * 64 + j * 16 + fr) * 32 + kq8];
#pragma unroll
    for (int i = 0; i < 4; i++)
#pragma unroll
      for (int j = 0; j < 4; j++)
        acc[i][j] = MFMA16(a[i], b[j], acc[i][j]);
  }

  const float scale = (z == 0) ? 0.125f : 1.0f;
  short* dst01 = (z == 0) ? qo : ko;
#pragma unroll
  for (int i = 0; i < 4; i++) {
#pragma unroll
    for (int j = 0; j < 4; j++) {
#pragma unroll
      for (int r = 0; r < 4; r++) {
        int row = m0 + wr * 64 + i * 16 + (l >> 4) * 4 + r;
        int col = n0 + wc * 64 + j * 16 + fr;
        int bb = row >> 11, tt = row & (T_ - 1);
        int hh = col >> 6,  hd = col & (HD_ - 1);
        short v = f2bf(acc[i][j][r] * scale);
        if (z == 2)
          vto[(((size_t)bb * H_ + hh) * HD_ + hd) * T_ + tt] = v;
        else
          dst01[(((size_t)bb * H_ + hh) * T_ + tt) * HD_ + hd] = v;
      }
    }
  }
}

// ---------------------------------------------------------------------------
// Column sums of V (for fully-masked rows): vs[bh*64+hd] = sum_t V[bh][t][hd]
// ---------------------------------------------------------------------------
__global__ __launch_bounds__(256) void vsum_kernel(const short* __restrict__ vt,
                                                   float* __restrict__ vs)
{
  __shared__ float red[256];
  int bh = blockIdx.x;
  int tid = threadIdx.x;
  int hd = tid & 63, part = tid >> 6;
  const short* src = vt + ((size_t)bh * HD_ + hd) * T_ + part * 512;
  float s = 0.f;
  for (int i = 0; i < 512; i += 4) {
    short4v v = *(const short4v*)(src + i);
    s += bf2f(v.x) + bf2f(v.y) + bf2f(v.z) + bf2f(v.w);
  }
  red[tid] = s;
  __syncthreads();
  if (part == 0)
    vs[(size_t)bh * HD_ + hd] = red[hd] + red[64 + hd] + red[128 + hd] + red[192 + hd];
}

// ---------------------------------------------------------------------------
// Attention: two-pass flash, batch-fused, split-K across 2 waves.
// 1-D grid 2048 WGs x 128 thr. wgid -> (h via &7|..: XCD-local K/V) and
// tile jt = 127 - (wgid>>4) (heavy-first). Wave w handles interleaved
// 64-col chunks (k0 = w*64, step 128). Bias read once per pass for BOTH
// batches. m/l merged across waves via LDS (1 barrier); PV partials merged
// via LDS overlay of wave0's transpose buffer (1 barrier).
// ---------------------------------------------------------------------------
__global__ __launch_bounds__(128, 4) void attn_kernel(
    const short* __restrict__ qw, const short* __restrict__ kw, const short* __restrict__ vt,
    const float* __restrict__ bias, const int* __restrict__ mask,
    const int* __restrict__ causal_p, const float* __restrict__ vsum,
    float* __restrict__ attn_out, short* __restrict__ outh)
{
  __shared__ float s_t[2][2][16][68];   // [wave][batch][row][col(+pad)]
  __shared__ float ml_l[2][2][16][2];   // [wave][batch][row][{m,l}]
  __shared__ float mrow_l[2][16];       // merged m per [batch][row]
  float* pv = &s_t[0][0][0][0];         // overlay: [2][16][64] PV partials (8KB < wave0's 8.7KB)

  const int tid = threadIdx.x;
  const int w = tid >> 6, l = tid & 63;
  const int fr = l & 15, q4 = l >> 4, kq8 = q4 * 8;
  const int wgid = blockIdx.x;
  const int h  = (wgid & 7) | (((wgid >> 3) & 1) << 3);
  const int jt = 127 - (wgid >> 4);
  const int q0w = jt * 16;
  const int causal = *causal_p;
  const int L = causal ? (q0w + 16) : T_;
  const int KEND = (L + 63) & ~63;
  const float invT = 1.0f / (float)T_;

  const short* Kb0 = kw + ((size_t)0 * H_ + h) * T_ * HD_;
  const short* Kb1 = kw + ((size_t)1 * H_ + h) * T_ * HD_;
  const short* Vb0 = vt + ((size_t)0 * H_ + h) * HD_ * T_;
  const short* Vb1 = vt + ((size_t)1 * H_ + h) * HD_ * T_;
  const float* biasb = bias + ((size_t)h * T_ + q0w) * T_;

  bf16x8v qa[2][2];
#pragma unroll
  for (int b = 0; b < 2; b++) {
    const short* qp = qw + (((size_t)b * H_ + h) * T_ + q0w + fr) * HD_;
    qa[b][0] = *(const bf16x8v*)(qp + kq8);
    qa[b][1] = *(const bf16x8v*)(qp + 32 + kq8);
  }

  float m4[2][4], l4[2][4];
#pragma unroll
  for (int b = 0; b < 2; b++)
#pragma unroll
    for (int r = 0; r < 4; r++) { m4[b][r] = -3e38f; l4[b][r] = 0.f; }

  // ---------------- pass 1: online m,l over own chunks ----------------
  for (int k0 = w * 64; k0 < KEND; k0 += 128) {
#pragma unroll
    for (int t = 0; t < 4; t++) {
      const int kcol = k0 + t * 16 + fr;
      bf16x8v kA0 = *(const bf16x8v*)(Kb0 + (size_t)kcol * HD_ + kq8);
      bf16x8v kA1 = *(const bf16x8v*)(Kb0 + (size_t)kcol * HD_ + 32 + kq8);
      bf16x8v kB0 = *(const bf16x8v*)(Kb1 + (size_t)kcol * HD_ + kq8);
      bf16x8v kB1 = *(const bf16x8v*)(Kb1 + (size_t)kcol * HD_ + 32 + kq8);
      float bi[4];
      const float* bp = biasb + (size_t)(q4 * 4) * T_ + kcol;
#pragma unroll
      for (int r = 0; r < 4; r++) bi[r] = bp[(size_t)r * T_];
      int mk0 = mask[kcol];
      int mk1 = mask[T_ + kcol];
      f32x4 s0 = {0.f, 0.f, 0.f, 0.f}, s1 = {0.f, 0.f, 0.f, 0.f};
      s0 = MFMA16(qa[0][0], kA0, s0); s0 = MFMA16(qa[0][1], kA1, s0);
      s1 = MFMA16(qa[1][0], kB0, s1); s1 = MFMA16(qa[1][1], kB1, s1);
#pragma unroll
      for (int r = 0; r < 4; r++) {
        bool cok = (!causal) || (kcol <= q0w + q4 * 4 + r);
        float sv0 = (mk0 && cok) ? (s0[r] + bi[r]) : -1e9f;
        float sv1 = (mk1 && cok) ? (s1[r] + bi[r]) : -1e9f;
        float d0 = sv0 - m4[0][r];
        float e0 = __expf(-fabsf(d0));
        l4[0][r] = (d0 > 0.f) ? (l4[0][r] * e0 + 1.f) : (l4[0][r] + e0);
        m4[0][r] = fmaxf(m4[0][r], sv0);
        float d1 = sv1 - m4[1][r];
        float e1 = __expf(-fabsf(d1));
        l4[1][r] = (d1 > 0.f) ? (l4[1][r] * e1 + 1.f) : (l4[1][r] + e1);
        m4[1][r] = fmaxf(m4[1][r], sv1);
      }
    }
  }
  // reduce across the 16 fr lanes
#pragma unroll
  for (int b = 0; b < 2; b++)
#pragma unroll
    for (int r = 0; r < 4; r++) {
#pragma unroll
      for (int off = 1; off < 16; off <<= 1) {
        float om = __shfl_xor(m4[b][r], off);
        float ol = __shfl_xor(l4[b][r], off);
        float nm = fmaxf(m4[b][r], om);
        l4[b][r] = l4[b][r] * __expf(m4[b][r] - nm) + ol * __expf(om - nm);
        m4[b][r] = nm;
      }
    }
  if (fr == 0) {
#pragma unroll
    for (int b = 0; b < 2; b++)
#pragma unroll
      for (int r = 0; r < 4; r++) {
        ml_l[w][b][q4 * 4 + r][0] = m4[b][r];
        ml_l[w][b][q4 * 4 + r][1] = l4[b][r];
      }
  }
  __syncthreads();

  // ---------------- merge halves -> lse, flags ----------------
  float lse[2][4];
  bool fm[2][4];
#pragma unroll
  for (int b = 0; b < 2; b++)
#pragma unroll
    for (int r = 0; r < 4; r++) {
      int row = q4 * 4 + r;
      float ma = ml_l[0][b][row][0], la = ml_l[0][b][row][1];
      float mb = ml_l[1][b][row][0], lb = ml_l[1][b][row][1];
      float M = fmaxf(ma, mb);
      float lsum = la * __expf(ma - M) + lb * __expf(mb - M);
      fm[b][r] = (M <= -0.5e9f);
      lse[b][r] = M + __logf(lsum);
      if (fr == 0) mrow_l[b][row] = M;
    }

  // ---------------- pass 2: p, coalesced NT attn store, PV ----------------
  f32x4 oacc[2][4] = {};
  for (int k0 = w * 64; k0 < KEND; k0 += 128) {
#pragma unroll
    for (int t = 0; t < 4; t++) {
      const int kcol = k0 + t * 16 + fr;
      bf16x8v kA0 = *(const bf16x8v*)(Kb0 + (size_t)kcol * HD_ + kq8);
      bf16x8v kA1 = *(const bf16x8v*)(Kb0 + (size_t)kcol * HD_ + 32 + kq8);
      bf16x8v kB0 = *(const bf16x8v*)(Kb1 + (size_t)kcol * HD_ + kq8);
      bf16x8v kB1 = *(const bf16x8v*)(Kb1 + (size_t)kcol * HD_ + 32 + kq8);
      float bi[4];
      const float* bp = biasb + (size_t)(q4 * 4) * T_ + kcol;
#pragma unroll
      for (int r = 0; r < 4; r++) bi[r] = bp[(size_t)r * T_];
      int mk0 = mask[kcol];
      int mk1 = mask[T_ + kcol];
      f32x4 s0 = {0.f, 0.f, 0.f, 0.f}, s1 = {0.f, 0.f, 0.f, 0.f};
      s0 = MFMA16(qa[0][0], kA0, s0); s0 = MFMA16(qa[0][1], kA1, s0);
      s1 = MFMA16(qa[1][0], kB0, s1); s1 = MFMA16(qa[1][1], kB1, s1);
#pragma unroll
      for (int r = 0; r < 4; r++) {
        bool cok = (!causal) || (kcol <= q0w + q4 * 4 + r);
        float sv0 = (mk0 && cok) ? (s0[r] + bi[r]) : -1e9f;
        float sv1 = (mk1 && cok) ? (s1[r] + bi[r]) : -1e9f;
        float p0 = fm[0][r] ? 0.f : __expf(sv0 - lse[0][r]);
        float p1 = fm[1][r] ? 0.f : __expf(sv1 - lse[1][r]);
        s_t[w][0][q4 * 4 + r][t * 16 + fr] = p0;
        s_t[w][1][q4 * 4 + r][t * 16 + fr] = p1;
      }
    }
#pragma unroll
    for (int b = 0; b < 2; b++) {
      float* arowb = attn_out + (((size_t)b * H_ + h) * T_ + q0w) * T_;
#pragma unroll
      for (int jj = 0; jj < 4; jj++) {
        int row = 4 * jj + q4;
        f32x4 pvv = *(const f32x4*)&s_t[w][b][row][fr * 4];
        bool fmj = mrow_l[b][row] <= -0.5e9f;
        f32x4 ov;
        ov[0] = fmj ? invT : pvv[0];
        ov[1] = fmj ? invT : pvv[1];
        ov[2] = fmj ? invT : pvv[2];
        ov[3] = fmj ? invT : pvv[3];
        __builtin_nontemporal_store(ov, (f32x4*)(arowb + (size_t)row * T_ + k0 + fr * 4));
      }
      const short* Vbb = b ? Vb1 : Vb0;
#pragma unroll
      for (int ks = 0; ks < 2; ks++) {
        f32x4 pa0 = *(const f32x4*)&s_t[w][b][fr][ks * 32 + kq8];
        f32x4 pa1 = *(const f32x4*)&s_t[w][b][fr][ks * 32 + kq8 + 4];
        bf16x8v pa;
#pragma unroll
        for (int i = 0; i < 4; i++) { pa[i] = f2bf(pa0[i]); pa[4 + i] = f2bf(pa1[i]); }
#pragma unroll
        for (int n0 = 0; n0 < 4; n0++) {
          bf16x8v vv = *(const bf16x8v*)&Vbb[(size_t)(n0 * 16 + fr) * T_ + k0 + ks * 32 + kq8];
          oacc[b][n0] = MFMA16(pa, vv, oacc[b][n0]);
        }
      }
    }
  }

  // ---------------- PV merge + outh + tail fill ----------------
  if (w == 0) {
#pragma unroll
    for (int b = 0; b < 2; b++)
#pragma unroll
      for (int n0 = 0; n0 < 4; n0++)
#pragma unroll
        for (int r = 0; r < 4; r++)
          pv[(b * 16 + q4 * 4 + r) * 64 + n0 * 16 + fr] = oacc[b][n0][r];
  }
  __syncthreads();
  if (w == 1) {
#pragma unroll
    for (int b = 0; b < 2; b++)
#pragma unroll
      for (int n0 = 0; n0 < 4; n0++)
#pragma unroll
        for (int r = 0; r < 4; r++) {
          int row = q4 * 4 + r, col = n0 * 16 + fr;
          float val = oacc[b][n0][r] + pv[(b * 16 + row) * 64 + col];
          if (fm[b][r]) val = vsum[((size_t)b * H_ + h) * HD_ + col] * invT;
          outh[(((size_t)b * H_ + h) * T_ + q0w + row) * HD_ + col] = f2bf(val);
        }
  } else if (KEND < T_) {
#pragma unroll
    for (int b = 0; b < 2; b++) {
      for (int row = 0; row < 16; row++) {
        float fill = (mrow_l[b][row] <= -0.5e9f) ? invT : 0.f;
        f32x4 fv = {fill, fill, fill, fill};
        float* rp = attn_out + (((size_t)b * H_ + h) * T_ + q0w + row) * T_;
        for (int c = KEND + l * 4; c < T_; c += 256)
          __builtin_nontemporal_store(fv, (f32x4*)(rp + c));
      }
    }
  }
}

// ---------------------------------------------------------------------------
// Output GEMM: out = out_h(4096x1024 logical) * Wo^T, fp32 output
// ---------------------------------------------------------------------------
__global__ __launch_bounds__(256) void out_gemm(
    const short* __restrict__ Ah, const short* __restrict__ Bw, float* __restrict__ Co)
{
  __shared__ short As[128 * 32];
  __shared__ short Bs[128 * 32];
  const int m0 = blockIdx.x * 128;
  const int n0 = blockIdx.y * 128;
  const int tid = threadIdx.x;
  const int w = tid >> 6, l = tid & 63;
  const int wr = w >> 1, wc = w & 1;
  const int fr = l & 15, kq8 = (l >> 4) * 8;
  const int srow = tid >> 2, scol = (tid & 3) * 8;

  f32x4 acc[4][4] = {};

  for (int k0 = 0; k0 < DM; k0 += 32) {
    __syncthreads();
    int kk = k0 + scol;
    int hh = kk >> 6, hd = kk & 63;
    {
      int m1 = m0 + srow;
      const short* src1 = Ah + (((size_t)(m1 >> 11) * H_ + hh) * T_ + (m1 & (T_ - 1))) * HD_ + hd;
      GLOAD_LDS16(src1, (char*)As + tid * 16);
      int m2 = m0 + 64 + srow;
      const short* src2 = Ah + (((size_t)(m2 >> 11) * H_ + hh) * T_ + (m2 & (T_ - 1))) * HD_ + hd;
      GLOAD_LDS16(src2, (char*)As + 4096 + tid * 16);
    }
    GLOAD_LDS16(Bw + (size_t)(n0 + srow) * DM + kk,      (char*)Bs + tid * 16);
    GLOAD_LDS16(Bw + (size_t)(n0 + 64 + srow) * DM + kk, (char*)Bs + 4096 + tid * 16);
    __syncthreads();
    bf16x8v a[4], b[4];
#pragma unroll
    for (int i = 0; i < 4; i++) a[i] = *(const bf16x8v*)&As[(wr * 64 + i * 16 + fr) * 32 + kq8];
#pragma unroll
    for (int j = 0; j < 4; j++) b[j] = *(const bf16x8v*)&Bs[(wc * 64 + j * 16 + fr) * 32 + kq8];
#pragma unroll
    for (int i = 0; i < 4; i++)
#pragma unroll
      for (int j = 0; j < 4; j++)
        acc[i][j] = MFMA16(a[i], b[j], acc[i][j]);
  }

#pragma unroll
  for (int i = 0; i < 4; i++)
#pragma unroll
    for (int j = 0; j < 4; j++)
#pragma unroll
      for (int r = 0; r < 4; r++) {
        int row = m0 + wr * 64 + i * 16 + (l >> 4) * 4 + r;
        int col = n0 + wc * 64 + j * 16 + fr;
        Co[(size_t)row * DM + col] = acc[i][j][r];
      }
}

// ---------------------------------------------------------------------------
extern "C" void kernel_launch(void* const* d_in, const int* in_sizes, int n_in,
                              void* d_out, int out_size, void* d_ws, size_t ws_size,
                              hipStream_t stream)
{
  const float* x_q  = (const float*)d_in[0];
  const float* x_k  = (const float*)d_in[1];
  const float* x_v  = (const float*)d_in[2];
  const int*   mask = (const int*)d_in[3];
  const int*   causal = (const int*)d_in[4];
  const float* bias = (const float*)d_in[5];
  const float* Wq   = (const float*)d_in[6];
  const float* Wk   = (const float*)d_in[7];
  const float* Wv   = (const float*)d_in[8];
  const float* Wo   = (const float*)d_in[9];

  char* ws = (char*)d_ws;
  const size_t XB = (size_t)B_ * T_ * DM * 2;   // 8 MB
  const size_t WB = (size_t)DM * DM * 2;        // 2 MB
  short* xq_b = (short*)(ws + 0 * XB);
  short* xk_b = (short*)(ws + 1 * XB);
  short* xv_b = (short*)(ws + 2 * XB);
  short* wq_b = (short*)(ws + 3 * XB + 0 * WB);
  short* wk_b = (short*)(ws + 3 * XB + 1 * WB);
  short* wv_b = (short*)(ws + 3 * XB + 2 * WB);
  short* wo_b = (short*)(ws + 3 * XB + 3 * WB);
  short* q_ws  = (short*)(ws + 3 * XB + 4 * WB);
  short* k_ws  = (short*)(ws + 4 * XB + 4 * WB);
  short* vt_ws = (short*)(ws + 5 * XB + 4 * WB);
  short* oh_ws = (short*)(ws + 6 * XB + 4 * WB);
  float* vs_ws = (float*)(ws + 7 * XB + 4 * WB);

  float* out0 = (float*)d_out;
  float* attn = out0 + (size_t)B_ * T_ * DM;

  conv_kernel<<<dim3(4096, 7, 1), 256, 0, stream>>>(
      x_q, x_k, x_v, Wq, Wk, Wv, Wo,
      xq_b, xk_b, xv_b, wq_b, wk_b, wv_b, wo_b);

  proj_gemm<<<dim3(32, 8, 3), 256, 0, stream>>>(
      xq_b, xk_b, xv_b, wq_b, wk_b, wv_b, q_ws, k_ws, vt_ws);

  vsum_kernel<<<dim3(32, 1, 1), 256, 0, stream>>>(vt_ws, vs_ws);

  attn_kernel<<<dim3(2048, 1, 1), 128, 0, stream>>>(
      q_ws, k_ws, vt_ws, bias, mask, causal, vs_ws, attn, oh_ws);

  out_gemm<<<dim3(32, 8, 1), 256, 0, stream>>>(oh_ws, wo_b, out0);
}

// Round 6
// 455.810 us; speedup vs baseline: 1.3709x; 1.0651x over previous
//
#include <hip/hip_runtime.h>
#include <hip/hip_bf16.h>
#include <hip/hip_fp16.h>

#define B_ 2
#define T_ 2048
#define DM 1024
#define H_ 16
#define HD_ 64

typedef __attribute__((ext_vector_type(8))) short bf16x8v;
typedef __attribute__((ext_vector_type(4))) short short4v;
typedef __attribute__((ext_vector_type(4))) float f32x4;

__device__ __forceinline__ short f2bf(float f){
  unsigned u = __builtin_bit_cast(unsigned, f);
  u += 0x7fffu + ((u >> 16) & 1u);
  return (short)(u >> 16);
}
__device__ __forceinline__ float bf2f(short s){
  unsigned u = ((unsigned)(unsigned short)s) << 16;
  return __builtin_bit_cast(float, u);
}

#define GLOAD_LDS16(g, l) \
  __builtin_amdgcn_global_load_lds((const __attribute__((address_space(1))) unsigned int*)(g), \
                                   (__attribute__((address_space(3))) unsigned int*)(l), 16, 0, 0)

#define MFMA16(a, b, c) __builtin_amdgcn_mfma_f32_16x16x32_bf16((a), (b), (c), 0, 0, 0)

// ---------------------------------------------------------------------------
// fp32 -> bf16 conversion for 3 activations (4M elems) + 4 weights (1M elems)
// ---------------------------------------------------------------------------
__global__ __launch_bounds__(256) void conv_kernel(
    const float* __restrict__ s0, const float* __restrict__ s1, const float* __restrict__ s2,
    const float* __restrict__ s3, const float* __restrict__ s4, const float* __restrict__ s5,
    const float* __restrict__ s6,
    short* __restrict__ d0, short* __restrict__ d1, short* __restrict__ d2,
    short* __restrict__ d3, short* __restrict__ d4, short* __restrict__ d5,
    short* __restrict__ d6)
{
  int y = blockIdx.y;
  const float* s; short* d; int n;
  switch (y) {
    case 0: s = s0; d = d0; n = B_*T_*DM; break;
    case 1: s = s1; d = d1; n = B_*T_*DM; break;
    case 2: s = s2; d = d2; n = B_*T_*DM; break;
    case 3: s = s3; d = d3; n = DM*DM;   break;
    case 4: s = s4; d = d4; n = DM*DM;   break;
    case 5: s = s5; d = d5; n = DM*DM;   break;
    default: s = s6; d = d6; n = DM*DM;  break;
  }
  int i = (blockIdx.x * 256 + threadIdx.x) * 4;
  if (i >= n) return;
  float4 f = *(const float4*)(s + i);
  short4v o;
  o.x = f2bf(f.x); o.y = f2bf(f.y); o.z = f2bf(f.z); o.w = f2bf(f.w);
  *(short4v*)(d + i) = o;
}

// ---------------------------------------------------------------------------
// Projection GEMM: C = X(4096x1024) * W^T(1024x1024), bf16 MFMA, 128x128 tile.
// z=0: Q (scaled 1/8) -> [b,h,t,hd]; z=1: K -> [b,h,t,hd]; z=2: V -> [b,h,hd,t]
// ---------------------------------------------------------------------------
__global__ __launch_bounds__(256) void proj_gemm(
    const short* __restrict__ xq, const short* __restrict__ xk, const short* __restrict__ xv,
    const short* __restrict__ wq, const short* __restrict__ wk, const short* __restrict__ wv,
    short* __restrict__ qo, short* __restrict__ ko, short* __restrict__ vto)
{
  __shared__ short As[128 * 32];
  __shared__ short Bs[128 * 32];
  const int z = blockIdx.z;
  const short* A  = (z == 0) ? xq : (z == 1) ? xk : xv;
  const short* Bw = (z == 0) ? wq : (z == 1) ? wk : wv;
  const int m0 = blockIdx.x * 128;
  const int n0 = blockIdx.y * 128;
  const int tid = threadIdx.x;
  const int w = tid >> 6, l = tid & 63;
  const int wr = w >> 1, wc = w & 1;
  const int fr = l & 15, kq8 = (l >> 4) * 8;
  const int srow = tid >> 2, scol = (tid & 3) * 8;

  f32x4 acc[4][4] = {};

  for (int k0 = 0; k0 < DM; k0 += 32) {
    __syncthreads();
    GLOAD_LDS16(A  + (size_t)(m0 + srow) * DM + k0 + scol,      (char*)As + tid * 16);
    GLOAD_LDS16(A  + (size_t)(m0 + 64 + srow) * DM + k0 + scol, (char*)As + 4096 + tid * 16);
    GLOAD_LDS16(Bw + (size_t)(n0 + srow) * DM + k0 + scol,      (char*)Bs + tid * 16);
    GLOAD_LDS16(Bw + (size_t)(n0 + 64 + srow) * DM + k0 + scol, (char*)Bs + 4096 + tid * 16);
    __syncthreads();
    bf16x8v a[4], b[4];
#pragma unroll
    for (int i = 0; i < 4; i++) a[i] = *(const bf16x8v*)&As[(wr * 64 + i * 16 + fr) * 32 + kq8];
#pragma unroll
    for (int j = 0; j < 4; j++) b[j] = *(const bf16x8v*)&Bs[(wc * 64 + j * 16 + fr) * 32 + kq8];
#pragma unroll
    for (int i = 0; i < 4; i++)
#pragma unroll
      for (int j = 0; j < 4; j++)
        acc[i][j] = MFMA16(a[i], b[j], acc[i][j]);
  }

  const float scale = (z == 0) ? 0.125f : 1.0f;
  short* dst01 = (z == 0) ? qo : ko;
#pragma unroll
  for (int i = 0; i < 4; i++) {
#pragma unroll
    for (int j = 0; j < 4; j++) {
#pragma unroll
      for (int r = 0; r < 4; r++) {
        int row = m0 + wr * 64 + i * 16 + (l >> 4) * 4 + r;
        int col = n0 + wc * 64 + j * 16 + fr;
        int bb = row >> 11, tt = row & (T_ - 1);
        int hh = col >> 6,  hd = col & (HD_ - 1);
        short v = f2bf(acc[i][j][r] * scale);
        if (z == 2)
          vto[(((size_t)bb * H_ + hh) * HD_ + hd) * T_ + tt] = v;
        else
          dst01[(((size_t)bb * H_ + hh) * T_ + tt) * HD_ + hd] = v;
      }
    }
  }
}

// ---------------------------------------------------------------------------
// Column sums of V (for fully-masked rows): vs[bh*64+hd] = sum_t V[bh][t][hd]
// ---------------------------------------------------------------------------
__global__ __launch_bounds__(256) void vsum_kernel(const short* __restrict__ vt,
                                                   float* __restrict__ vs)
{
  __shared__ float red[256];
  int bh = blockIdx.x;
  int tid = threadIdx.x;
  int hd = tid & 63, part = tid >> 6;
  const short* src = vt + ((size_t)bh * HD_ + hd) * T_ + part * 512;
  float s = 0.f;
  for (int i = 0; i < 512; i += 4) {
    short4v v = *(const short4v*)(src + i);
    s += bf2f(v.x) + bf2f(v.y) + bf2f(v.z) + bf2f(v.w);
  }
  red[tid] = s;
  __syncthreads();
  if (part == 0)
    vs[(size_t)bh * HD_ + hd] = red[hd] + red[64 + hd] + red[128 + hd] + red[192 + hd];
}

// ---------------------------------------------------------------------------
// Attention v6: swapped-operand QK^T (S^T = K.Q^T) so each lane owns ONE
// q-row with 4 consecutive k-cols per MFMA reg:
//   - bias: one f32x4/lane/t-tile (dense 64B lines)
//   - attn store: direct coalesced NT f32x4 (no LDS transpose)
//   - online softmax lane-local, chunk-batched (no per-element branchy update)
// Two-pass flash, batch-fused, split-K 2 waves. Grid 2048 x 128 threads.
// ---------------------------------------------------------------------------
__global__ __launch_bounds__(128, 4) void attn_kernel(
    const short* __restrict__ qw, const short* __restrict__ kw, const short* __restrict__ vt,
    const float* __restrict__ bias, const int* __restrict__ mask,
    const int* __restrict__ causal_p, const float* __restrict__ vsum,
    float* __restrict__ attn_out, short* __restrict__ outh)
{
  __shared__ short p_l[2][2][16][68];   // [wave][batch][q-row][k] bf16 p-tile (padded)
  __shared__ float ml_l[2][2][16][2];   // [wave][batch][row][{m,l}]
  __shared__ float mrow_l[2][16];       // merged max per [batch][row]
  float* pv = (float*)&p_l[0][0][0][0]; // overlay after barrier: [2][16][64] f32

  const int tid = threadIdx.x;
  const int w = tid >> 6, l = tid & 63;
  const int fr = l & 15, q4 = l >> 4, kq8 = q4 * 8;
  const int wgid = blockIdx.x;
  const int h  = (wgid & 7) | (((wgid >> 3) & 1) << 3);
  const int jt = 127 - (wgid >> 4);
  const int q0w = jt * 16;
  const int causal = *causal_p;
  const int L = causal ? (q0w + 16) : T_;
  const int KEND = (L + 63) & ~63;
  const float invT = 1.0f / (float)T_;
  const int qrow = q0w + fr;            // this lane's q-row (global)

  const short* Kb0 = kw + ((size_t)0 * H_ + h) * T_ * HD_;
  const short* Kb1 = kw + ((size_t)1 * H_ + h) * T_ * HD_;
  const short* Vb0 = vt + ((size_t)0 * H_ + h) * HD_ * T_;
  const short* Vb1 = vt + ((size_t)1 * H_ + h) * HD_ * T_;
  const float* brow = bias + ((size_t)h * T_ + qrow) * T_;

  bf16x8v qa[2][2];
#pragma unroll
  for (int b = 0; b < 2; b++) {
    const short* qp = qw + (((size_t)b * H_ + h) * T_ + qrow) * HD_;
    qa[b][0] = *(const bf16x8v*)(qp + kq8);
    qa[b][1] = *(const bf16x8v*)(qp + 32 + kq8);
  }

  float m_[2] = {-3e38f, -3e38f}, l_[2] = {0.f, 0.f};

  // ---------------- pass 1: chunk-batched online max/sum ----------------
  for (int k0 = w * 64; k0 < KEND; k0 += 128) {
    f32x4 sv[2][4];
#pragma unroll
    for (int t = 0; t < 4; t++) {
      const int kb = k0 + t * 16;
      const short* kp0 = Kb0 + (size_t)(kb + fr) * HD_ + kq8;
      const short* kp1 = Kb1 + (size_t)(kb + fr) * HD_ + kq8;
      f32x4 a0 = {0.f, 0.f, 0.f, 0.f}, a1 = {0.f, 0.f, 0.f, 0.f};
      a0 = MFMA16(*(const bf16x8v*)kp0,        qa[0][0], a0);
      a0 = MFMA16(*(const bf16x8v*)(kp0 + 32), qa[0][1], a0);
      a1 = MFMA16(*(const bf16x8v*)kp1,        qa[1][0], a1);
      a1 = MFMA16(*(const bf16x8v*)(kp1 + 32), qa[1][1], a1);
      f32x4 bi = *(const f32x4*)(brow + kb + q4 * 4);
      int4 mk0 = *(const int4*)(mask + kb + q4 * 4);
      int4 mk1 = *(const int4*)(mask + T_ + kb + q4 * 4);
      int mka[4] = {mk0.x, mk0.y, mk0.z, mk0.w};
      int mkb[4] = {mk1.x, mk1.y, mk1.z, mk1.w};
      if (!causal || (kb + 15 <= q0w)) {
#pragma unroll
        for (int r = 0; r < 4; r++) {
          sv[0][t][r] = mka[r] ? (a0[r] + bi[r]) : -1e9f;
          sv[1][t][r] = mkb[r] ? (a1[r] + bi[r]) : -1e9f;
        }
      } else {
#pragma unroll
        for (int r = 0; r < 4; r++) {
          bool cok = (kb + q4 * 4 + r) <= qrow;
          sv[0][t][r] = (mka[r] && cok) ? (a0[r] + bi[r]) : -1e9f;
          sv[1][t][r] = (mkb[r] && cok) ? (a1[r] + bi[r]) : -1e9f;
        }
      }
    }
#pragma unroll
    for (int b = 0; b < 2; b++) {
      float tm = -3e38f;
#pragma unroll
      for (int t = 0; t < 4; t++)
#pragma unroll
        for (int r = 0; r < 4; r++) tm = fmaxf(tm, sv[b][t][r]);
      float nm = fmaxf(m_[b], tm);
      float ss = 0.f;
#pragma unroll
      for (int t = 0; t < 4; t++)
#pragma unroll
        for (int r = 0; r < 4; r++) ss += __expf(sv[b][t][r] - nm);
      l_[b] = l_[b] * __expf(m_[b] - nm) + ss;
      m_[b] = nm;
    }
  }
  // combine the 4 q4 lane-groups (same q-row)
#pragma unroll
  for (int b = 0; b < 2; b++) {
#pragma unroll
    for (int off = 16; off < 64; off <<= 1) {
      float om = __shfl_xor(m_[b], off);
      float ol = __shfl_xor(l_[b], off);
      float nm = fmaxf(m_[b], om);
      l_[b] = l_[b] * __expf(m_[b] - nm) + ol * __expf(om - nm);
      m_[b] = nm;
    }
  }
  if (q4 == 0) {
#pragma unroll
    for (int b = 0; b < 2; b++) {
      ml_l[w][b][fr][0] = m_[b];
      ml_l[w][b][fr][1] = l_[b];
    }
  }
  __syncthreads();

  // merge across the two waves -> lse, fm (per lane's q-row fr)
  float lse[2];
  bool fm[2];
#pragma unroll
  for (int b = 0; b < 2; b++) {
    float ma = ml_l[0][b][fr][0], la = ml_l[0][b][fr][1];
    float mb = ml_l[1][b][fr][0], lb = ml_l[1][b][fr][1];
    float M = fmaxf(ma, mb);
    float lsum = la * __expf(ma - M) + lb * __expf(mb - M);
    fm[b] = (M <= -0.5e9f);
    lse[b] = M + __logf(lsum);
    if (q4 == 0 && w == 0) mrow_l[b][fr] = M;
  }

  // ---------------- pass 2: p, coalesced NT store, PV ----------------
  f32x4 oacc[2][4] = {};
  for (int k0 = w * 64; k0 < KEND; k0 += 128) {
#pragma unroll
    for (int t = 0; t < 4; t++) {
      const int kb = k0 + t * 16;
      const short* kp0 = Kb0 + (size_t)(kb + fr) * HD_ + kq8;
      const short* kp1 = Kb1 + (size_t)(kb + fr) * HD_ + kq8;
      f32x4 a0 = {0.f, 0.f, 0.f, 0.f}, a1 = {0.f, 0.f, 0.f, 0.f};
      a0 = MFMA16(*(const bf16x8v*)kp0,        qa[0][0], a0);
      a0 = MFMA16(*(const bf16x8v*)(kp0 + 32), qa[0][1], a0);
      a1 = MFMA16(*(const bf16x8v*)kp1,        qa[1][0], a1);
      a1 = MFMA16(*(const bf16x8v*)(kp1 + 32), qa[1][1], a1);
      f32x4 bi = *(const f32x4*)(brow + kb + q4 * 4);
      int4 mk0 = *(const int4*)(mask + kb + q4 * 4);
      int4 mk1 = *(const int4*)(mask + T_ + kb + q4 * 4);
      int mka[4] = {mk0.x, mk0.y, mk0.z, mk0.w};
      int mkb[4] = {mk1.x, mk1.y, mk1.z, mk1.w};
      f32x4 p0, p1;
      if (!causal || (kb + 15 <= q0w)) {
#pragma unroll
        for (int r = 0; r < 4; r++) {
          p0[r] = mka[r] ? __expf(a0[r] + bi[r] - lse[0]) : 0.f;
          p1[r] = mkb[r] ? __expf(a1[r] + bi[r] - lse[1]) : 0.f;
        }
      } else {
#pragma unroll
        for (int r = 0; r < 4; r++) {
          bool cok = (kb + q4 * 4 + r) <= qrow;
          p0[r] = (mka[r] && cok) ? __expf(a0[r] + bi[r] - lse[0]) : 0.f;
          p1[r] = (mkb[r] && cok) ? __expf(a1[r] + bi[r] - lse[1]) : 0.f;
        }
      }
      f32x4 st0, st1;
#pragma unroll
      for (int r = 0; r < 4; r++) {
        st0[r] = fm[0] ? invT : p0[r];
        st1[r] = fm[1] ? invT : p1[r];
      }
      __builtin_nontemporal_store(st0,
          (f32x4*)(attn_out + (((size_t)0 * H_ + h) * T_ + qrow) * T_ + kb + q4 * 4));
      __builtin_nontemporal_store(st1,
          (f32x4*)(attn_out + (((size_t)1 * H_ + h) * T_ + qrow) * T_ + kb + q4 * 4));
      short4v pb0, pb1;
#pragma unroll
      for (int r = 0; r < 4; r++) { pb0[r] = f2bf(p0[r]); pb1[r] = f2bf(p1[r]); }
      *(short4v*)&p_l[w][0][fr][t * 16 + q4 * 4] = pb0;
      *(short4v*)&p_l[w][1][fr][t * 16 + q4 * 4] = pb1;
    }
    // PV for this 64-col chunk
#pragma unroll
    for (int ks = 0; ks < 2; ks++) {
      bf16x8v pa0 = *(const bf16x8v*)&p_l[w][0][fr][ks * 32 + kq8];
      bf16x8v pa1 = *(const bf16x8v*)&p_l[w][1][fr][ks * 32 + kq8];
#pragma unroll
      for (int n0 = 0; n0 < 4; n0++) {
        bf16x8v vv0 = *(const bf16x8v*)&Vb0[(size_t)(n0 * 16 + fr) * T_ + k0 + ks * 32 + kq8];
        bf16x8v vv1 = *(const bf16x8v*)&Vb1[(size_t)(n0 * 16 + fr) * T_ + k0 + ks * 32 + kq8];
        oacc[0][n0] = MFMA16(pa0, vv0, oacc[0][n0]);
        oacc[1][n0] = MFMA16(pa1, vv1, oacc[1][n0]);
      }
    }
  }

  // ---------------- PV merge (LDS overlay) + outh ----------------
  __syncthreads();                      // everyone done with p_l
  if (w == 0) {
#pragma unroll
    for (int b = 0; b < 2; b++)
#pragma unroll
      for (int n0 = 0; n0 < 4; n0++)
#pragma unroll
        for (int r = 0; r < 4; r++)
          pv[(b * 16 + q4 * 4 + r) * 64 + n0 * 16 + fr] = oacc[b][n0][r];
  }
  __syncthreads();
  if (w == 1) {
#pragma unroll
    for (int b = 0; b < 2; b++)
#pragma unroll
      for (int n0 = 0; n0 < 4; n0++)
#pragma unroll
        for (int r = 0; r < 4; r++) {
          int row = q4 * 4 + r, col = n0 * 16 + fr;
          float val = oacc[b][n0][r] + pv[(b * 16 + row) * 64 + col];
          if (mrow_l[b][row] <= -0.5e9f)
            val = vsum[((size_t)b * H_ + h) * HD_ + col] * invT;
          outh[(((size_t)b * H_ + h) * T_ + q0w + row) * HD_ + col] = f2bf(val);
        }
  }

  // ---------------- tail fill [KEND, T) (both waves, split) ----------------
  if (KEND < T_) {
    float fill0 = fm[0] ? invT : 0.f;
    float fill1 = fm[1] ? invT : 0.f;
    f32x4 fv0 = {fill0, fill0, fill0, fill0};
    f32x4 fv1 = {fill1, fill1, fill1, fill1};
    float* r0 = attn_out + (((size_t)0 * H_ + h) * T_ + qrow) * T_;
    float* r1 = attn_out + (((size_t)1 * H_ + h) * T_ + qrow) * T_;
    for (int cb = KEND + w * 64; cb < T_; cb += 128) {
#pragma unroll
      for (int t = 0; t < 4; t++) {
        __builtin_nontemporal_store(fv0, (f32x4*)(r0 + cb + t * 16 + q4 * 4));
        __builtin_nontemporal_store(fv1, (f32x4*)(r1 + cb + t * 16 + q4 * 4));
      }
    }
  }
}

// ---------------------------------------------------------------------------
// Output GEMM: out = out_h(4096x1024 logical) * Wo^T, fp32 output
// ---------------------------------------------------------------------------
__global__ __launch_bounds__(256) void out_gemm(
    const short* __restrict__ Ah, const short* __restrict__ Bw, float* __restrict__ Co)
{
  __shared__ short As[128 * 32];
  __shared__ short Bs[128 * 32];
  const int m0 = blockIdx.x * 128;
  const int n0 = blockIdx.y * 128;
  const int tid = threadIdx.x;
  const int w = tid >> 6, l = tid & 63;
  const int wr = w >> 1, wc = w & 1;
  const int fr = l & 15, kq8 = (l >> 4) * 8;
  const int srow = tid >> 2, scol = (tid & 3) * 8;

  f32x4 acc[4][4] = {};

  for (int k0 = 0; k0 < DM; k0 += 32) {
    __syncthreads();
    int kk = k0 + scol;
    int hh = kk >> 6, hd = kk & 63;
    {
      int m1 = m0 + srow;
      const short* src1 = Ah + (((size_t)(m1 >> 11) * H_ + hh) * T_ + (m1 & (T_ - 1))) * HD_ + hd;
      GLOAD_LDS16(src1, (char*)As + tid * 16);
      int m2 = m0 + 64 + srow;
      const short* src2 = Ah + (((size_t)(m2 >> 11) * H_ + hh) * T_ + (m2 & (T_ - 1))) * HD_ + hd;
      GLOAD_LDS16(src2, (char*)As + 4096 + tid * 16);
    }
    GLOAD_LDS16(Bw + (size_t)(n0 + srow) * DM + kk,      (char*)Bs + tid * 16);
    GLOAD_LDS16(Bw + (size_t)(n0 + 64 + srow) * DM + kk, (char*)Bs + 4096 + tid * 16);
    __syncthreads();
    bf16x8v a[4], b[4];
#pragma unroll
    for (int i = 0; i < 4; i++) a[i] = *(const bf16x8v*)&As[(wr * 64 + i * 16 + fr) * 32 + kq8];
#pragma unroll
    for (int j = 0; j < 4; j++) b[j] = *(const bf16x8v*)&Bs[(wc * 64 + j * 16 + fr) * 32 + kq8];
#pragma unroll
    for (int i = 0; i < 4; i++)
#pragma unroll
      for (int j = 0; j < 4; j++)
        acc[i][j] = MFMA16(a[i], b[j], acc[i][j]);
  }

#pragma unroll
  for (int i = 0; i < 4; i++)
#pragma unroll
    for (int j = 0; j < 4; j++)
#pragma unroll
      for (int r = 0; r < 4; r++) {
        int row = m0 + wr * 64 + i * 16 + (l >> 4) * 4 + r;
        int col = n0 + wc * 64 + j * 16 + fr;
        Co[(size_t)row * DM + col] = acc[i][j][r];
      }
}

// ---------------------------------------------------------------------------
extern "C" void kernel_launch(void* const* d_in, const int* in_sizes, int n_in,
                              void* d_out, int out_size, void* d_ws, size_t ws_size,
                              hipStream_t stream)
{
  const float* x_q  = (const float*)d_in[0];
  const float* x_k  = (const float*)d_in[1];
  const float* x_v  = (const float*)d_in[2];
  const int*   mask = (const int*)d_in[3];
  const int*   causal = (const int*)d_in[4];
  const float* bias = (const float*)d_in[5];
  const float* Wq   = (const float*)d_in[6];
  const float* Wk   = (const float*)d_in[7];
  const float* Wv   = (const float*)d_in[8];
  const float* Wo   = (const float*)d_in[9];

  char* ws = (char*)d_ws;
  const size_t XB = (size_t)B_ * T_ * DM * 2;   // 8 MB
  const size_t WB = (size_t)DM * DM * 2;        // 2 MB
  short* xq_b = (short*)(ws + 0 * XB);
  short* xk_b = (short*)(ws + 1 * XB);
  short* xv_b = (short*)(ws + 2 * XB);
  short* wq_b = (short*)(ws + 3 * XB + 0 * WB);
  short* wk_b = (short*)(ws + 3 * XB + 1 * WB);
  short* wv_b = (short*)(ws + 3 * XB + 2 * WB);
  short* wo_b = (short*)(ws + 3 * XB + 3 * WB);
  short* q_ws  = (short*)(ws + 3 * XB + 4 * WB);
  short* k_ws  = (short*)(ws + 4 * XB + 4 * WB);
  short* vt_ws = (short*)(ws + 5 * XB + 4 * WB);
  short* oh_ws = (short*)(ws + 6 * XB + 4 * WB);
  float* vs_ws = (float*)(ws + 7 * XB + 4 * WB);

  float* out0 = (float*)d_out;
  float* attn = out0 + (size_t)B_ * T_ * DM;

  conv_kernel<<<dim3(4096, 7, 1), 256, 0, stream>>>(
      x_q, x_k, x_v, Wq, Wk, Wv, Wo,
      xq_b, xk_b, xv_b, wq_b, wk_b, wv_b, wo_b);

  proj_gemm<<<dim3(32, 8, 3), 256, 0, stream>>>(
      xq_b, xk_b, xv_b, wq_b, wk_b, wv_b, q_ws, k_ws, vt_ws);

  vsum_kernel<<<dim3(32, 1, 1), 256, 0, stream>>>(vt_ws, vs_ws);

  attn_kernel<<<dim3(2048, 1, 1), 128, 0, stream>>>(
      q_ws, k_ws, vt_ws, bias, mask, causal, vs_ws, attn, oh_ws);

  out_gemm<<<dim3(32, 8, 1), 256, 0, stream>>>(oh_ws, wo_b, out0);
}